// Round 1
// baseline (256.926 us; speedup 1.0000x reference)
//
#include <hip/hip_runtime.h>
#include <cmath>

#define NPTS 262144
#define NLVL 16

struct Meta {
    float scale[NLVL];
    unsigned off[NLVL];
    unsigned hsize[NLVL];
    unsigned res[NLVL];
    unsigned kind[NLVL];   // 0 = linear, 1 = hash (hsize pow2), 2 = hash generic
};

__global__ __launch_bounds__(256) void grid_enc(
    const float* __restrict__ means, const float* __restrict__ emb,
    float* __restrict__ out, Meta meta)
{
    const int p = blockIdx.x * 256 + threadIdx.x;

    const float mx = means[3 * p + 0];
    const float my = means[3 * p + 1];
    const float mz = means[3 * p + 2];
    const float x = (mx + 1.0f) * 0.5f;
    const float y = (my + 1.0f) * 0.5f;
    const float z = (mz + 1.0f) * 0.5f;

    float o[2 * NLVL];

    const float2* __restrict__ emb2 = (const float2*)emb;

#pragma unroll
    for (int l = 0; l < NLVL; ++l) {
        const float s = meta.scale[l];
        const unsigned off = meta.off[l];
        const unsigned hs  = meta.hsize[l];
        const unsigned r   = meta.res[l];
        const unsigned kind = meta.kind[l];

        const float px = x * s, py = y * s, pz = z * s;
        const float gx = floorf(px), gy = floorf(py), gz = floorf(pz);
        const float fx = px - gx, fy = py - gy, fz = pz - gz;
        const unsigned ix = (unsigned)gx, iy = (unsigned)gy, iz = (unsigned)gz;

        const float wx[2] = {1.0f - fx, fx};
        const float wy[2] = {1.0f - fy, fy};
        const float wz[2] = {1.0f - fz, fz};

        float a0 = 0.0f, a1 = 0.0f;

#pragma unroll
        for (int c = 0; c < 8; ++c) {
            const unsigned bx = c & 1, by = (c >> 1) & 1, bz = c >> 2;
            const unsigned cx = ix + bx, cy = iy + by, cz = iz + bz;
            unsigned idx;
            if (kind == 1) {
                // hash, hsize is power of two
                idx = (cx ^ (cy * 2654435761u) ^ (cz * 805459861u)) & (hs - 1u);
            } else if (kind == 2) {
                idx = (cx ^ (cy * 2654435761u) ^ (cz * 805459861u)) % hs;
            } else {
                idx = cx + cy * r + cz * r * r;
                if (idx >= hs) idx %= hs;   // edge case x==1.0; ~never taken
            }
            const float2 f = emb2[off + idx];
            const float w = wx[bx] * wy[by] * wz[bz];
            a0 += w * f.x;
            a1 += w * f.y;
        }
        o[2 * l]     = a0;
        o[2 * l + 1] = a1;
    }

    float4* o4 = (float4*)(out + (size_t)p * (2 * NLVL));
#pragma unroll
    for (int k = 0; k < (2 * NLVL) / 4; ++k)
        o4[k] = ((const float4*)o)[k];
}

extern "C" void kernel_launch(void* const* d_in, const int* in_sizes, int n_in,
                              void* d_out, int out_size, void* d_ws, size_t ws_size,
                              hipStream_t stream)
{
    const float* means = (const float*)d_in[0];
    const float* emb   = (const float*)d_in[1];
    float* out         = (float*)d_out;

    Meta m;
    const double lg = log2(1.38191288);
    unsigned off = 0;
    for (int l = 0; l < NLVL; ++l) {
        // _encode: scale = 2**(l*lg)*16 - 1 ; res = ceil(scale)+1
        const double scale_d = pow(2.0, (double)l * lg) * 16.0 - 1.0;
        m.scale[l] = (float)scale_d;
        const unsigned res_enc = (unsigned)ceil(scale_d) + 1u;

        // _grid_meta: res = ceil(16 * 1.38191288**l); p = min(2^19, res^3) rounded up to 8
        const double gres_d = ceil(16.0 * pow(1.38191288, (double)l));
        unsigned long long r3 = (unsigned long long)gres_d;
        r3 = r3 * r3 * r3;
        unsigned long long pl = r3 < (1ull << 19) ? r3 : (1ull << 19);
        pl = (pl + 7ull) / 8ull * 8ull;

        m.off[l]   = off;
        m.hsize[l] = (unsigned)pl;
        m.res[l]   = res_enc;

        unsigned long long re3 = (unsigned long long)res_enc;
        re3 = re3 * re3 * re3;
        if (re3 > pl) {
            // hash level
            const unsigned hs = (unsigned)pl;
            m.kind[l] = ((hs & (hs - 1u)) == 0u) ? 1u : 2u;
        } else {
            m.kind[l] = 0u;
        }
        off += (unsigned)pl;
    }

    grid_enc<<<NPTS / 256, 256, 0, stream>>>(means, emb, out, m);
}

// Round 2
// 247.630 us; speedup vs baseline: 1.0375x; 1.0375x over previous
//
#include <hip/hip_runtime.h>
#include <cmath>

#define NPTS 262144
#define NLVL 16
#define NDENSE 5
#define NHASH 11
#define HASH_MASK 0x7FFFFu

struct MetaD {
    float scale[NDENSE];
    unsigned off[NDENSE];   // float2-element offset into emb
    unsigned res[NDENSE];
};
struct MetaH {
    float scale[NHASH];
    unsigned off[NHASH];    // float2-element offset into emb
};

// ---------------- dense (linear-indexed) levels 0..4 ----------------
__global__ __launch_bounds__(256) void enc_dense(
    const float* __restrict__ means, const float* __restrict__ emb,
    float* __restrict__ out, MetaD meta)
{
    const int p = blockIdx.x * 256 + threadIdx.x;
    const int l = blockIdx.y;                 // wave-uniform

    const float x = (means[3 * p + 0] + 1.0f) * 0.5f;
    const float y = (means[3 * p + 1] + 1.0f) * 0.5f;
    const float z = (means[3 * p + 2] + 1.0f) * 0.5f;

    const float s   = meta.scale[l];
    const unsigned off = meta.off[l];
    const unsigned r   = meta.res[l];

    const float px = x * s, py = y * s, pz = z * s;
    const float gx = floorf(px), gy = floorf(py), gz = floorf(pz);
    const float fx = px - gx, fy = py - gy, fz = pz - gz;
    const unsigned ix = (unsigned)gx, iy = (unsigned)gy, iz = (unsigned)gz;

    // linear index: cx + cy*r + cz*r*r  (provably < hsize for x in [0,1))
    const unsigned base = ix + iy * r + iz * r * r + off;
    const unsigned dy = r, dz = r * r;

    const float2* __restrict__ emb2 = (const float2*)emb;
    float2 f[8];
    f[0] = emb2[base];
    f[1] = emb2[base + 1];
    f[2] = emb2[base + dy];
    f[3] = emb2[base + dy + 1];
    f[4] = emb2[base + dz];
    f[5] = emb2[base + dz + 1];
    f[6] = emb2[base + dz + dy];
    f[7] = emb2[base + dz + dy + 1];

    const float wx0 = 1.0f - fx, wy0 = 1.0f - fy, wz0 = 1.0f - fz;
    float a0 = 0.0f, a1 = 0.0f;
    {
        const float w00 = wz0 * wy0, w01 = wz0 * fy, w10 = fz * wy0, w11 = fz * fy;
        a0 = w00 * (wx0 * f[0].x + fx * f[1].x) + w01 * (wx0 * f[2].x + fx * f[3].x)
           + w10 * (wx0 * f[4].x + fx * f[5].x) + w11 * (wx0 * f[6].x + fx * f[7].x);
        a1 = w00 * (wx0 * f[0].y + fx * f[1].y) + w01 * (wx0 * f[2].y + fx * f[3].y)
           + w10 * (wx0 * f[4].y + fx * f[5].y) + w11 * (wx0 * f[6].y + fx * f[7].y);
    }

    float2* out2 = (float2*)out;
    out2[(size_t)p * NLVL + l] = make_float2(a0, a1);
}

// ---------------- hash levels 5..15 (hsize = 2^19, pow2 mask) ----------------
__global__ __launch_bounds__(256) void enc_hash(
    const float* __restrict__ means, const float* __restrict__ emb,
    float* __restrict__ out, MetaH meta)
{
    const int p = blockIdx.x * 256 + threadIdx.x;
    const int l = blockIdx.y;                 // wave-uniform, 0..10 -> level l+5

    const float x = (means[3 * p + 0] + 1.0f) * 0.5f;
    const float y = (means[3 * p + 1] + 1.0f) * 0.5f;
    const float z = (means[3 * p + 2] + 1.0f) * 0.5f;

    const float s    = meta.scale[l];
    const unsigned off = meta.off[l];

    const float px = x * s, py = y * s, pz = z * s;
    const float gx = floorf(px), gy = floorf(py), gz = floorf(pz);
    const float fx = px - gx, fy = py - gy, fz = pz - gz;
    const unsigned ix = (unsigned)gx, iy = (unsigned)gy, iz = (unsigned)gz;

    const unsigned hy0 = iy * 2654435761u;
    const unsigned hy1 = hy0 + 2654435761u;
    const unsigned hz0 = iz * 805459861u;
    const unsigned hz1 = hz0 + 805459861u;

    const float2* __restrict__ emb2 = (const float2*)emb;
    float2 f[8];
    f[0] = emb2[off + ((ix       ^ hy0 ^ hz0) & HASH_MASK)];
    f[1] = emb2[off + (((ix + 1) ^ hy0 ^ hz0) & HASH_MASK)];
    f[2] = emb2[off + ((ix       ^ hy1 ^ hz0) & HASH_MASK)];
    f[3] = emb2[off + (((ix + 1) ^ hy1 ^ hz0) & HASH_MASK)];
    f[4] = emb2[off + ((ix       ^ hy0 ^ hz1) & HASH_MASK)];
    f[5] = emb2[off + (((ix + 1) ^ hy0 ^ hz1) & HASH_MASK)];
    f[6] = emb2[off + ((ix       ^ hy1 ^ hz1) & HASH_MASK)];
    f[7] = emb2[off + (((ix + 1) ^ hy1 ^ hz1) & HASH_MASK)];

    const float wx0 = 1.0f - fx, wy0 = 1.0f - fy, wz0 = 1.0f - fz;
    float a0, a1;
    {
        const float w00 = wz0 * wy0, w01 = wz0 * fy, w10 = fz * wy0, w11 = fz * fy;
        a0 = w00 * (wx0 * f[0].x + fx * f[1].x) + w01 * (wx0 * f[2].x + fx * f[3].x)
           + w10 * (wx0 * f[4].x + fx * f[5].x) + w11 * (wx0 * f[6].x + fx * f[7].x);
        a1 = w00 * (wx0 * f[0].y + fx * f[1].y) + w01 * (wx0 * f[2].y + fx * f[3].y)
           + w10 * (wx0 * f[4].y + fx * f[5].y) + w11 * (wx0 * f[6].y + fx * f[7].y);
    }

    float2* out2 = (float2*)out;
    out2[(size_t)p * NLVL + (l + NDENSE)] = make_float2(a0, a1);
}

extern "C" void kernel_launch(void* const* d_in, const int* in_sizes, int n_in,
                              void* d_out, int out_size, void* d_ws, size_t ws_size,
                              hipStream_t stream)
{
    const float* means = (const float*)d_in[0];
    const float* emb   = (const float*)d_in[1];
    float* out         = (float*)d_out;

    MetaD md;
    MetaH mh;
    const double lg = log2(1.38191288);
    unsigned off = 0;
    for (int l = 0; l < NLVL; ++l) {
        const double scale_d = pow(2.0, (double)l * lg) * 16.0 - 1.0;
        const unsigned res_enc = (unsigned)ceil(scale_d) + 1u;

        const double gres_d = ceil(16.0 * pow(1.38191288, (double)l));
        unsigned long long r3 = (unsigned long long)gres_d;
        r3 = r3 * r3 * r3;
        unsigned long long pl = r3 < (1ull << 19) ? r3 : (1ull << 19);
        pl = (pl + 7ull) / 8ull * 8ull;

        if (l < NDENSE) {
            md.scale[l] = (float)scale_d;
            md.off[l]   = off;
            md.res[l]   = res_enc;
        } else {
            mh.scale[l - NDENSE] = (float)scale_d;
            mh.off[l - NDENSE]   = off;
        }
        off += (unsigned)pl;
    }

    dim3 blk(256, 1, 1);
    enc_dense<<<dim3(NPTS / 256, NDENSE, 1), blk, 0, stream>>>(means, emb, out, md);
    enc_hash <<<dim3(NPTS / 256, NHASH, 1), blk, 0, stream>>>(means, emb, out, mh);
}

// Round 3
// 203.998 us; speedup vs baseline: 1.2595x; 1.2139x over previous
//
#include <hip/hip_runtime.h>
#include <cmath>

#define NPTS 262144
#define NLVL 16
#define NDENSE 5
#define NHASH 11
#define HASH_MASK 0x7FFFFu

struct MetaD { float scale[NDENSE]; unsigned off[NDENSE]; unsigned res[NDENSE]; };
struct MetaH { float scale[NHASH]; unsigned off[NHASH]; };

// ---------------- dense (linear-indexed) levels 0..4 ----------------
__global__ __launch_bounds__(256) void enc_dense(
    const float* __restrict__ means, const float* __restrict__ emb,
    float2* __restrict__ dst, int lvl_major, MetaD meta)
{
    const int p = blockIdx.x * 256 + threadIdx.x;
    const int l = blockIdx.y;                 // wave-uniform level

    const float x = (means[3 * p + 0] + 1.0f) * 0.5f;
    const float y = (means[3 * p + 1] + 1.0f) * 0.5f;
    const float z = (means[3 * p + 2] + 1.0f) * 0.5f;

    const float s      = meta.scale[l];
    const unsigned off = meta.off[l];
    const unsigned r   = meta.res[l];

    const float px = x * s, py = y * s, pz = z * s;
    const float gx = floorf(px), gy = floorf(py), gz = floorf(pz);
    const float fx = px - gx, fy = py - gy, fz = pz - gz;
    const unsigned ix = (unsigned)gx, iy = (unsigned)gy, iz = (unsigned)gz;

    const unsigned base = ix + iy * r + iz * r * r + off;
    const unsigned dy = r, dz = r * r;

    const float2* __restrict__ emb2 = (const float2*)emb;
    float2 f[8];
    f[0] = emb2[base];           f[1] = emb2[base + 1];
    f[2] = emb2[base + dy];      f[3] = emb2[base + dy + 1];
    f[4] = emb2[base + dz];      f[5] = emb2[base + dz + 1];
    f[6] = emb2[base + dz + dy]; f[7] = emb2[base + dz + dy + 1];

    const float wx0 = 1.0f - fx, wy0 = 1.0f - fy, wz0 = 1.0f - fz;
    const float w00 = wz0 * wy0, w01 = wz0 * fy, w10 = fz * wy0, w11 = fz * fy;
    const float a0 = w00 * (wx0 * f[0].x + fx * f[1].x) + w01 * (wx0 * f[2].x + fx * f[3].x)
                   + w10 * (wx0 * f[4].x + fx * f[5].x) + w11 * (wx0 * f[6].x + fx * f[7].x);
    const float a1 = w00 * (wx0 * f[0].y + fx * f[1].y) + w01 * (wx0 * f[2].y + fx * f[3].y)
                   + w10 * (wx0 * f[4].y + fx * f[5].y) + w11 * (wx0 * f[6].y + fx * f[7].y);

    const size_t di = lvl_major ? ((size_t)l * NPTS + p) : ((size_t)p * NLVL + l);
    dst[di] = make_float2(a0, a1);
}

// ---------------- hash level inner (hsize = 2^19) ----------------
__device__ __forceinline__ float2 hash_level(
    const float* __restrict__ emb, unsigned off, float s,
    float x, float y, float z)
{
    const float px = x * s, py = y * s, pz = z * s;
    const float gx = floorf(px), gy = floorf(py), gz = floorf(pz);
    const float fx = px - gx, fy = py - gy, fz = pz - gz;
    const unsigned ix = (unsigned)gx, iy = (unsigned)gy, iz = (unsigned)gz;

    const unsigned hy0 = iy * 2654435761u, hy1 = hy0 + 2654435761u;
    const unsigned hz0 = iz * 805459861u,  hz1 = hz0 + 805459861u;
    const unsigned hyz[4] = {hy0 ^ hz0, hy1 ^ hz0, hy0 ^ hz1, hy1 ^ hz1};

    const float wy0 = 1.0f - fy, wz0 = 1.0f - fz;
    const float wc[4] = {wy0 * wz0, fy * wz0, wy0 * fz, fy * fz};
    const float wx0 = 1.0f - fx;

    const float2* __restrict__ emb2 = (const float2*)emb;
    const float4* __restrict__ emb4 = (const float4*)emb;

    float a0 = 0.0f, a1 = 0.0f;
    if ((ix & 1u) == 0u) {
        // x-corners (ix, ix+1) hash to (i0, i0^1): one float4 covers both
#pragma unroll
        for (int c = 0; c < 4; ++c) {
            const unsigned i0 = (ix ^ hyz[c]) & HASH_MASK;
            const float4 f = emb4[(off + (i0 & ~1u)) >> 1];
            const bool sw = (i0 & 1u);
            const float c0x = sw ? f.z : f.x, c0y = sw ? f.w : f.y;
            const float c1x = sw ? f.x : f.z, c1y = sw ? f.y : f.w;
            a0 += wc[c] * (wx0 * c0x + fx * c1x);
            a1 += wc[c] * (wx0 * c0y + fx * c1y);
        }
    } else {
#pragma unroll
        for (int c = 0; c < 4; ++c) {
            const unsigned i0 = (ix        ^ hyz[c]) & HASH_MASK;
            const unsigned i1 = ((ix + 1u) ^ hyz[c]) & HASH_MASK;
            const float2 f0 = emb2[off + i0];
            const float2 f1 = emb2[off + i1];
            a0 += wc[c] * (wx0 * f0.x + fx * f1.x);
            a1 += wc[c] * (wx0 * f0.y + fx * f1.y);
        }
    }
    return make_float2(a0, a1);
}

// hash levels 5..15, XCD-affine: xcd = blockIdx.x & 7 owns specific levels.
// slots < 512: level il = xcd (il 0..7), 512-pt chunks 0..511.
// slots >= 512: il = 8 + (xcd>>1) for xcd<6; chunk = (slot-512)*2 + (xcd&1).
__global__ __launch_bounds__(256) void enc_hash(
    const float* __restrict__ means, const float* __restrict__ emb,
    float2* __restrict__ dst, int lvl_major, MetaH meta)
{
    const unsigned b = blockIdx.x;
    const unsigned xcd = b & 7u, slot = b >> 3;
    unsigned il, chunk;
    if (slot < 512u) { il = xcd; chunk = slot; }
    else {
        if (xcd >= 6u) return;
        il = 8u + (xcd >> 1);
        chunk = ((slot - 512u) << 1) | (xcd & 1u);
    }
    const float s      = meta.scale[il];
    const unsigned off = meta.off[il];
    const unsigned lvl = il + NDENSE;

    const unsigned p0 = chunk * 512u + threadIdx.x;

#pragma unroll
    for (int pp = 0; pp < 2; ++pp) {
        const unsigned p = p0 + pp * 256u;
        const float x = (means[3 * p + 0] + 1.0f) * 0.5f;
        const float y = (means[3 * p + 1] + 1.0f) * 0.5f;
        const float z = (means[3 * p + 2] + 1.0f) * 0.5f;
        const float2 a = hash_level(emb, off, s, x, y, z);
        const size_t di = lvl_major ? ((size_t)lvl * NPTS + p) : ((size_t)p * NLVL + lvl);
        dst[di] = a;
    }
}

// ---------------- transpose ws[level][point] -> out[point][level] ----------------
__global__ __launch_bounds__(256) void transpose_out(
    const float2* __restrict__ ws, float* __restrict__ out)
{
    const int p = blockIdx.x * 256 + threadIdx.x;
    float4 o[8];
    float2* o2 = (float2*)o;
#pragma unroll
    for (int l = 0; l < NLVL; ++l)
        o2[l] = ws[(size_t)l * NPTS + p];
    float4* out4 = (float4*)(out + (size_t)p * (2 * NLVL));
#pragma unroll
    for (int k = 0; k < 8; ++k)
        out4[k] = o[k];
}

extern "C" void kernel_launch(void* const* d_in, const int* in_sizes, int n_in,
                              void* d_out, int out_size, void* d_ws, size_t ws_size,
                              hipStream_t stream)
{
    const float* means = (const float*)d_in[0];
    const float* emb   = (const float*)d_in[1];
    float* out         = (float*)d_out;

    MetaD md;
    MetaH mh;
    const double lg = log2(1.38191288);
    unsigned off = 0;
    for (int l = 0; l < NLVL; ++l) {
        const double scale_d = pow(2.0, (double)l * lg) * 16.0 - 1.0;
        const unsigned res_enc = (unsigned)ceil(scale_d) + 1u;

        const double gres_d = ceil(16.0 * pow(1.38191288, (double)l));
        unsigned long long r3 = (unsigned long long)gres_d;
        r3 = r3 * r3 * r3;
        unsigned long long pl = r3 < (1ull << 19) ? r3 : (1ull << 19);
        pl = (pl + 7ull) / 8ull * 8ull;

        if (l < NDENSE) {
            md.scale[l] = (float)scale_d;
            md.off[l]   = off;
            md.res[l]   = res_enc;
        } else {
            mh.scale[l - NDENSE] = (float)scale_d;
            mh.off[l - NDENSE]   = off;
        }
        off += (unsigned)pl;
    }

    const size_t ws_needed = (size_t)NLVL * NPTS * sizeof(float2);  // 32 MB
    const bool use_ws = ws_size >= ws_needed;
    float2* dst = use_ws ? (float2*)d_ws : (float2*)out;
    const int lvl_major = use_ws ? 1 : 0;

    enc_dense<<<dim3(NPTS / 256, NDENSE, 1), 256, 0, stream>>>(means, emb, dst, lvl_major, md);
    enc_hash <<<dim3(8 * 768, 1, 1),          256, 0, stream>>>(means, emb, dst, lvl_major, mh);
    if (use_ws)
        transpose_out<<<NPTS / 256, 256, 0, stream>>>((const float2*)d_ws, out);
}